// Round 4
// baseline (762.978 us; speedup 1.0000x reference)
//
#include <hip/hip_runtime.h>

#define NB 2
#define NH 16
#define SEQ 2048
#define HD 64

typedef __attribute__((ext_vector_type(8))) __bf16 bfrag8;
typedef __attribute__((ext_vector_type(4))) __bf16 bvec4;
typedef __attribute__((ext_vector_type(4))) float ffrag4;
typedef __attribute__((ext_vector_type(4))) float f32x4;   // native vector for nontemporal builtins

#define SCALE2 0.18033688011112042f   /* (1/sqrt(64)) * log2(e) */
#define MASKVAL (-3.0e38f)

__device__ __forceinline__ ffrag4 mfma16(bfrag8 a, bfrag8 b, ffrag4 c) {
    return __builtin_amdgcn_mfma_f32_16x16x32_bf16(a, b, c, 0, 0, 0);
}

// ---------------------------------------------------------------------------
// Prologue: per-iteration convert K -> bf16 (row-major) and V -> bf16
// transposed (Vt[d][s]) into workspace. K/V land in exactly the MFMA
// fragment-load layout, so the attention kernel reads fragments straight
// from global (L1/L2-resident) with NO LDS staging and NO barriers.
// ---------------------------------------------------------------------------
__global__ __launch_bounds__(256)
void cvt_kv(const float* __restrict__ Kg, const float* __restrict__ Vg,
            __bf16* __restrict__ Kw, __bf16* __restrict__ Vtw)
{
    const int bh = blockIdx.y;
    const int t0 = blockIdx.x * 64;          // s-tile base
    const int tid = threadIdx.x;

    const float* Kb = Kg + (size_t)bh * SEQ * HD;
    const float* Vb = Vg + (size_t)bh * SEQ * HD;
    __bf16* Kwb = Kw  + (size_t)bh * SEQ * HD;
    __bf16* Vwb = Vtw + (size_t)bh * SEQ * HD;   // layout [d][s]

    // K convert (layout-preserving)
    #pragma unroll
    for (int j = 0; j < 4; ++j) {
        int i = tid + 256 * j;
        int row = i >> 4, c4 = (i & 15) * 4;
        float4 v = *(const float4*)(Kb + (size_t)(t0 + row) * HD + c4);
        bvec4 w = { (__bf16)v.x, (__bf16)v.y, (__bf16)v.z, (__bf16)v.w };
        *(bvec4*)&Kwb[(size_t)(t0 + row) * HD + c4] = w;
    }

    // V transpose via LDS (scatter conflicts OK here -- runs once, tiny)
    __shared__ __align__(16) __bf16 Vs[64 * 72];
    #pragma unroll
    for (int j = 0; j < 4; ++j) {
        int i = tid + 256 * j;
        int row = i >> 4, c4 = (i & 15) * 4;
        float4 v = *(const float4*)(Vb + (size_t)(t0 + row) * HD + c4);
        Vs[(c4 + 0) * 72 + row] = (__bf16)v.x;
        Vs[(c4 + 1) * 72 + row] = (__bf16)v.y;
        Vs[(c4 + 2) * 72 + row] = (__bf16)v.z;
        Vs[(c4 + 3) * 72 + row] = (__bf16)v.w;
    }
    __syncthreads();
    #pragma unroll
    for (int j = 0; j < 2; ++j) {
        int i = tid + 256 * j;
        int d = i >> 3, c8 = (i & 7) * 8;
        bfrag8 w = *(bfrag8*)&Vs[d * 72 + c8];
        *(bfrag8*)&Vwb[(size_t)d * SEQ + t0 + c8] = w;
    }
}

// LDS layout (17408 B total):
//   [0, 17408)  P32 : per-wave fp32 P tile [4][16][68]
//   Qs (bf16 [64][72], 9216 B) aliases the front -- only used before pass 1.
__global__ __launch_bounds__(256, 4)
void attn_fwd(const float* __restrict__ Qg, const __bf16* __restrict__ Kw,
              const __bf16* __restrict__ Vtw, float* __restrict__ Og,
              float* __restrict__ Pg)
{
    const int bh   = blockIdx.y;
    const int qt   = (blockIdx.x + blockIdx.y) & 31;   // swizzle: balance causal load
    const int q0   = qt * 64;
    const int tid  = threadIdx.x;
    const int wave = tid >> 6;
    const int lane = tid & 63;
    const int l16  = lane & 15;
    const int quad = lane >> 4;

    const float*  Qb  = Qg  + (size_t)bh * SEQ * HD;
    const __bf16* Kwb = Kw  + (size_t)bh * SEQ * HD;
    const __bf16* Vwb = Vtw + (size_t)bh * SEQ * HD;
    float* Ob = Og + (size_t)bh * SEQ * HD;
    float* Pb = Pg + (size_t)bh * SEQ * SEQ;

    __shared__ __align__(16) char smem[17408];
    __bf16* Qs  = (__bf16*)smem;
    float*  P32 = (float*)smem;
    float*  Pw  = P32 + wave * (16 * 68);

    // ---- explicit zeros for fully-masked columns [q0+64, SEQ) ----
    {
        const f32x4 z4 = {0.f, 0.f, 0.f, 0.f};
        for (int r = 0; r < 64; ++r) {
            float* dst = Pb + (size_t)(q0 + r) * SEQ;
            for (int c = q0 + 64 + tid * 4; c < SEQ; c += 1024)
                __builtin_nontemporal_store(z4, (f32x4*)(dst + c));
        }
    }

    // ---- stage Q tile (64x64) -> LDS bf16, build A-frags ----
    #pragma unroll
    for (int j = 0; j < 4; ++j) {
        int i = tid + 256 * j;
        int row = i >> 4, c4 = (i & 15) * 4;
        float4 v = *(const float4*)(Qb + (size_t)(q0 + row) * HD + c4);
        bvec4 w = { (__bf16)v.x, (__bf16)v.y, (__bf16)v.z, (__bf16)v.w };
        *(bvec4*)&Qs[row * 72 + c4] = w;
    }
    __syncthreads();
    bfrag8 qf0 = *(bfrag8*)&Qs[(wave * 16 + l16) * 72 +  0 + quad * 8];
    bfrag8 qf1 = *(bfrag8*)&Qs[(wave * 16 + l16) * 72 + 32 + quad * 8];
    __syncthreads();   // all waves done reading Qs before P32 clobbers it

    const int nch   = q0 / 64 + 1;        // 64-wide chunks covering [0, q0+64)
    const int wrow  = q0 + wave * 16;
    const int myrow = wrow + quad * 4;

    float m_i[4], l_i[4], rl[4];
    #pragma unroll
    for (int r = 0; r < 4; ++r) { m_i[r] = MASKVAL; l_i[r] = 0.f; }

    // ======== pass 1: stats. Direct global K-fragment loads, NO barriers ====
    for (int ch = 0; ch < nch; ++ch) {
        const __bf16* Kc = Kwb + (size_t)(ch * 64) * HD;
        ffrag4 acc[4] = { {0,0,0,0},{0,0,0,0},{0,0,0,0},{0,0,0,0} };
        #pragma unroll
        for (int g = 0; g < 4; ++g) {
            bfrag8 b0 = *(const bfrag8*)(Kc + (g * 16 + l16) * HD + quad * 8);
            bfrag8 b1 = *(const bfrag8*)(Kc + (g * 16 + l16) * HD + 32 + quad * 8);
            acc[g] = mfma16(qf0, b0, acc[g]);
            acc[g] = mfma16(qf1, b1, acc[g]);
        }
        #pragma unroll
        for (int r = 0; r < 4; ++r) {
            const int row = myrow + r;
            float s0 = (ch * 64 +  0 + l16 <= row) ? acc[0][r] * SCALE2 : MASKVAL;
            float s1 = (ch * 64 + 16 + l16 <= row) ? acc[1][r] * SCALE2 : MASKVAL;
            float s2 = (ch * 64 + 32 + l16 <= row) ? acc[2][r] * SCALE2 : MASKVAL;
            float s3 = (ch * 64 + 48 + l16 <= row) ? acc[3][r] * SCALE2 : MASKVAL;
            float mn = fmaxf(fmaxf(s0, s1), fmaxf(s2, s3));
            mn = fmaxf(mn, m_i[r]);
            float e = exp2f(s0 - mn) + exp2f(s1 - mn)
                    + exp2f(s2 - mn) + exp2f(s3 - mn);
            l_i[r] = l_i[r] * exp2f(m_i[r] - mn) + e;
            m_i[r] = mn;
        }
    }

    // ---- one cross-lane merge per block (16-lane groups share rows) ----
    #pragma unroll
    for (int r = 0; r < 4; ++r) {
        float m = m_i[r], l = l_i[r];
        #pragma unroll
        for (int d = 1; d < 16; d <<= 1) {
            float om = __shfl_xor(m, d, 16);
            float ol = __shfl_xor(l, d, 16);
            float mn = fmaxf(m, om);
            l = l * exp2f(m - mn) + ol * exp2f(om - mn);
            m = mn;
        }
        m_i[r] = m;
        rl[r]  = 1.f / l;
    }

    // ======== pass 2: write P, accumulate O. No barriers; Pw is wave-private =
    ffrag4 oacc[4] = { {0,0,0,0},{0,0,0,0},{0,0,0,0},{0,0,0,0} };
    for (int ch = 0; ch < nch; ++ch) {
        const __bf16* Kc = Kwb + (size_t)(ch * 64) * HD;
        ffrag4 acc[4] = { {0,0,0,0},{0,0,0,0},{0,0,0,0},{0,0,0,0} };
        #pragma unroll
        for (int g = 0; g < 4; ++g) {
            bfrag8 b0 = *(const bfrag8*)(Kc + (g * 16 + l16) * HD + quad * 8);
            bfrag8 b1 = *(const bfrag8*)(Kc + (g * 16 + l16) * HD + 32 + quad * 8);
            acc[g] = mfma16(qf0, b0, acc[g]);
            acc[g] = mfma16(qf1, b1, acc[g]);
        }
        #pragma unroll
        for (int r = 0; r < 4; ++r) {
            const int row = myrow + r;
            #pragma unroll
            for (int g = 0; g < 4; ++g) {
                int col = ch * 64 + g * 16 + l16;
                float p = (col <= row)
                        ? exp2f(acc[g][r] * SCALE2 - m_i[r]) * rl[r] : 0.f;
                Pw[(quad * 4 + r) * 68 + g * 16 + l16] = p;
            }
        }
        asm volatile("s_waitcnt lgkmcnt(0)" ::: "memory");  // wave-private tile ready

        // coalesced fp32 P stores: 4x dwordx4 per lane (256B per row segment)
        #pragma unroll
        for (int t = 0; t < 4; ++t) {
            int row = (lane >> 4) + t * 4;
            f32x4 v = *(f32x4*)&Pw[row * 68 + (lane & 15) * 4];
            __builtin_nontemporal_store(v,
                (f32x4*)(Pb + (size_t)(wrow + row) * SEQ + ch * 64 + (lane & 15) * 4));
        }

        // PV: rebuild A-frags (bf16) from the fp32 LDS tile; V frags from global
        #pragma unroll
        for (int h = 0; h < 2; ++h) {
            float4 p0 = *(float4*)&Pw[l16 * 68 + h * 32 + quad * 8];
            float4 p1 = *(float4*)&Pw[l16 * 68 + h * 32 + quad * 8 + 4];
            bfrag8 pa = { (__bf16)p0.x, (__bf16)p0.y, (__bf16)p0.z, (__bf16)p0.w,
                          (__bf16)p1.x, (__bf16)p1.y, (__bf16)p1.z, (__bf16)p1.w };
            #pragma unroll
            for (int t = 0; t < 4; ++t) {
                bfrag8 bv = *(const bfrag8*)(Vwb + (size_t)(t * 16 + l16) * SEQ
                                             + ch * 64 + h * 32 + quad * 8);
                oacc[t] = mfma16(pa, bv, oacc[t]);
            }
        }
    }

    // ---- write O ----
    #pragma unroll
    for (int t = 0; t < 4; ++t)
        #pragma unroll
        for (int r = 0; r < 4; ++r)
            Ob[(size_t)(myrow + r) * HD + t * 16 + l16] = oacc[t][r];
}

extern "C" void kernel_launch(void* const* d_in, const int* in_sizes, int n_in,
                              void* d_out, int out_size, void* d_ws, size_t ws_size,
                              hipStream_t stream) {
    const float* Qg = (const float*)d_in[0];
    const float* Kg = (const float*)d_in[1];
    const float* Vg = (const float*)d_in[2];
    // d_in[3] (attn_mask) intentionally unused: mask is the fixed causal tril
    float* Og = (float*)d_out;
    float* Pg = Og + (size_t)NB * NH * SEQ * HD;

    // workspace: Kw (bf16, row-major) + Vtw (bf16, transposed [d][s]); 8.4 MB each
    __bf16* Kw  = (__bf16*)d_ws;
    __bf16* Vtw = Kw + (size_t)NB * NH * SEQ * HD;

    dim3 grid(SEQ / 64, NB * NH);
    cvt_kv<<<grid, dim3(256), 0, stream>>>(Kg, Vg, Kw, Vtw);
    attn_fwd<<<grid, dim3(256), 0, stream>>>(Qg, Kw, Vtw, Og, Pg);
}

// Round 5
// 646.675 us; speedup vs baseline: 1.1798x; 1.1798x over previous
//
#include <hip/hip_runtime.h>

#define NB 2
#define NH 16
#define SEQ 2048
#define HD 64

typedef __attribute__((ext_vector_type(8))) __bf16 bfrag8;
typedef __attribute__((ext_vector_type(4))) __bf16 bvec4;
typedef __attribute__((ext_vector_type(4))) float ffrag4;
typedef __attribute__((ext_vector_type(4))) float f32x4;   // native vector for nontemporal builtins

#define SCALE2 0.18033688011112042f   /* (1/sqrt(64)) * log2(e) */
#define MASKVAL (-3.0e38f)

__device__ __forceinline__ ffrag4 mfma16(bfrag8 a, bfrag8 b, ffrag4 c) {
    return __builtin_amdgcn_mfma_f32_16x16x32_bf16(a, b, c, 0, 0, 0);
}

// ---------------------------------------------------------------------------
// Prologue: per-iteration convert K -> bf16 (row-major) and V -> bf16
// transposed (Vt[d][s]) into workspace. Removes all fp32->bf16 converts and
// the 16-way-conflicted V^T scatter from the attention inner loop.
// ---------------------------------------------------------------------------
__global__ __launch_bounds__(256)
void cvt_kv(const float* __restrict__ Kg, const float* __restrict__ Vg,
            __bf16* __restrict__ Kw, __bf16* __restrict__ Vtw)
{
    const int bh = blockIdx.y;
    const int t0 = blockIdx.x * 64;          // s-tile base
    const int tid = threadIdx.x;

    const float* Kb = Kg + (size_t)bh * SEQ * HD;
    const float* Vb = Vg + (size_t)bh * SEQ * HD;
    __bf16* Kwb = Kw  + (size_t)bh * SEQ * HD;
    __bf16* Vwb = Vtw + (size_t)bh * SEQ * HD;   // layout [d][s]

    // K convert (layout-preserving)
    #pragma unroll
    for (int j = 0; j < 4; ++j) {
        int i = tid + 256 * j;
        int row = i >> 4, c4 = (i & 15) * 4;
        float4 v = *(const float4*)(Kb + (size_t)(t0 + row) * HD + c4);
        bvec4 w = { (__bf16)v.x, (__bf16)v.y, (__bf16)v.z, (__bf16)v.w };
        *(bvec4*)&Kwb[(size_t)(t0 + row) * HD + c4] = w;
    }

    // V transpose via LDS (scatter conflicts OK here -- runs once, tiny)
    __shared__ __align__(16) __bf16 Vs[64 * 72];
    #pragma unroll
    for (int j = 0; j < 4; ++j) {
        int i = tid + 256 * j;
        int row = i >> 4, c4 = (i & 15) * 4;
        float4 v = *(const float4*)(Vb + (size_t)(t0 + row) * HD + c4);
        Vs[(c4 + 0) * 72 + row] = (__bf16)v.x;
        Vs[(c4 + 1) * 72 + row] = (__bf16)v.y;
        Vs[(c4 + 2) * 72 + row] = (__bf16)v.z;
        Vs[(c4 + 3) * 72 + row] = (__bf16)v.w;
    }
    __syncthreads();
    #pragma unroll
    for (int j = 0; j < 2; ++j) {
        int i = tid + 256 * j;
        int d = i >> 3, c8 = (i & 7) * 8;
        bfrag8 w = *(bfrag8*)&Vs[d * 72 + c8];
        *(bfrag8*)&Vwb[(size_t)d * SEQ + t0 + c8] = w;
    }
}

// LDS layout (35840 B total -> 4 blocks/CU):
//   [0,      9216)  Ks  : K chunk  bf16 [64][72]
//   [9216,  18432)  Vts : V^T chunk bf16 [64][72]  (Vts[hd][k])
//   [18432, 35840)  P32 : per-wave fp32 P tile [4][16][68]; aliases Qs (bf16 [64][72])
__global__ __launch_bounds__(256, 4)
void attn_fwd(const float* __restrict__ Qg, const __bf16* __restrict__ Kw,
              const __bf16* __restrict__ Vtw, float* __restrict__ Og,
              float* __restrict__ Pg)
{
    const int bh   = blockIdx.y;
    const int qt   = (blockIdx.x + blockIdx.y) & 31;   // swizzle: balance causal load
    const int q0   = qt * 64;
    const int tid  = threadIdx.x;
    const int wave = tid >> 6;
    const int lane = tid & 63;
    const int l16  = lane & 15;
    const int quad = lane >> 4;

    const float*  Qb  = Qg  + (size_t)bh * SEQ * HD;
    const __bf16* Kwb = Kw  + (size_t)bh * SEQ * HD;
    const __bf16* Vwb = Vtw + (size_t)bh * SEQ * HD;
    float* Ob = Og + (size_t)bh * SEQ * HD;
    float* Pb = Pg + (size_t)bh * SEQ * SEQ;

    __shared__ __align__(16) char smem[35840];
    __bf16* Ks  = (__bf16*)smem;
    __bf16* Vts = (__bf16*)(smem + 9216);
    float*  P32 = (float*)(smem + 18432);
    __bf16* Qs  = (__bf16*)(smem + 18432);
    float*  Pw  = P32 + wave * (16 * 68);

    // staging decomposition: thread stages two 16B pieces of K (and V)
    const int s0r = tid >> 3,         s0c = (tid & 7) * 8;          // i = tid
    const int s1r = (tid + 256) >> 3, s1c = ((tid + 256) & 7) * 8;  // i = tid+256

    // ---- explicit zeros for fully-masked columns [q0+64, SEQ) ----
    {
        const f32x4 z4 = {0.f, 0.f, 0.f, 0.f};
        for (int r = 0; r < 64; ++r) {
            float* dst = Pb + (size_t)(q0 + r) * SEQ;
            for (int c = q0 + 64 + tid * 4; c < SEQ; c += 1024)
                __builtin_nontemporal_store(z4, (f32x4*)(dst + c));
        }
    }

    // ---- stage Q tile (64x64) -> LDS bf16, build A-frags ----
    #pragma unroll
    for (int j = 0; j < 4; ++j) {
        int i = tid + 256 * j;
        int row = i >> 4, c4 = (i & 15) * 4;
        float4 v = *(const float4*)(Qb + (size_t)(q0 + row) * HD + c4);
        bvec4 w = { (__bf16)v.x, (__bf16)v.y, (__bf16)v.z, (__bf16)v.w };
        *(bvec4*)&Qs[row * 72 + c4] = w;
    }
    __syncthreads();
    bfrag8 qf0 = *(bfrag8*)&Qs[(wave * 16 + l16) * 72 +  0 + quad * 8];
    bfrag8 qf1 = *(bfrag8*)&Qs[(wave * 16 + l16) * 72 + 32 + quad * 8];

    const int nch   = q0 / 64 + 1;        // 64-wide chunks covering [0, q0+64)
    const int wrow  = q0 + wave * 16;
    const int myrow = wrow + quad * 4;

    float m_i[4], l_i[4], rl[4];
    #pragma unroll
    for (int r = 0; r < 4; ++r) { m_i[r] = MASKVAL; l_i[r] = 0.f; }

    // ============ pass 1: stats, T14 prefetch (load ch+1 during compute of ch)
    bfrag8 kp0 = *(const bfrag8*)(Kwb + (size_t)s0r * HD + s0c);
    bfrag8 kp1 = *(const bfrag8*)(Kwb + (size_t)s1r * HD + s1c);
    for (int ch = 0; ch < nch; ++ch) {
        __syncthreads();                       // prev chunk's LDS reads done
        *(bfrag8*)&Ks[s0r * 72 + s0c] = kp0;   // (vmcnt waits folded in here)
        *(bfrag8*)&Ks[s1r * 72 + s1c] = kp1;
        __syncthreads();
        if (ch + 1 < nch) {                    // issue next chunk's loads now
            const __bf16* Kn = Kwb + (size_t)((ch + 1) * 64) * HD;
            kp0 = *(const bfrag8*)(Kn + (size_t)s0r * HD + s0c);
            kp1 = *(const bfrag8*)(Kn + (size_t)s1r * HD + s1c);
        }

        ffrag4 acc[4] = { {0,0,0,0},{0,0,0,0},{0,0,0,0},{0,0,0,0} };
        #pragma unroll
        for (int g = 0; g < 4; ++g) {
            bfrag8 b0 = *(bfrag8*)&Ks[(g * 16 + l16) * 72 + quad * 8];
            bfrag8 b1 = *(bfrag8*)&Ks[(g * 16 + l16) * 72 + 32 + quad * 8];
            acc[g] = mfma16(qf0, b0, acc[g]);
            acc[g] = mfma16(qf1, b1, acc[g]);
        }
        #pragma unroll
        for (int r = 0; r < 4; ++r) {
            const int row = myrow + r;
            float s0 = (ch * 64 +  0 + l16 <= row) ? acc[0][r] * SCALE2 : MASKVAL;
            float s1 = (ch * 64 + 16 + l16 <= row) ? acc[1][r] * SCALE2 : MASKVAL;
            float s2 = (ch * 64 + 32 + l16 <= row) ? acc[2][r] * SCALE2 : MASKVAL;
            float s3 = (ch * 64 + 48 + l16 <= row) ? acc[3][r] * SCALE2 : MASKVAL;
            float mn = fmaxf(fmaxf(s0, s1), fmaxf(s2, s3));
            mn = fmaxf(mn, m_i[r]);
            float e = exp2f(s0 - mn) + exp2f(s1 - mn)
                    + exp2f(s2 - mn) + exp2f(s3 - mn);
            l_i[r] = l_i[r] * exp2f(m_i[r] - mn) + e;
            m_i[r] = mn;
        }
    }

    // ---- one cross-lane merge per block (16-lane groups share rows) ----
    #pragma unroll
    for (int r = 0; r < 4; ++r) {
        float m = m_i[r], l = l_i[r];
        #pragma unroll
        for (int d = 1; d < 16; d <<= 1) {
            float om = __shfl_xor(m, d, 16);
            float ol = __shfl_xor(l, d, 16);
            float mn = fmaxf(m, om);
            l = l * exp2f(m - mn) + ol * exp2f(om - mn);
            m = mn;
        }
        m_i[r] = m;
        rl[r]  = 1.f / l;
    }

    // ============ pass 2: write P, accumulate O; T14 prefetch of K and V ====
    ffrag4 oacc[4] = { {0,0,0,0},{0,0,0,0},{0,0,0,0},{0,0,0,0} };
    bfrag8 vp0, vp1;
    kp0 = *(const bfrag8*)(Kwb + (size_t)s0r * HD + s0c);
    kp1 = *(const bfrag8*)(Kwb + (size_t)s1r * HD + s1c);
    vp0 = *(const bfrag8*)(Vwb + (size_t)s0r * SEQ + s0c);
    vp1 = *(const bfrag8*)(Vwb + (size_t)s1r * SEQ + s1c);
    for (int ch = 0; ch < nch; ++ch) {
        __syncthreads();                       // prev chunk's LDS reads done
        *(bfrag8*)&Ks [s0r * 72 + s0c] = kp0;
        *(bfrag8*)&Ks [s1r * 72 + s1c] = kp1;
        *(bfrag8*)&Vts[s0r * 72 + s0c] = vp0;
        *(bfrag8*)&Vts[s1r * 72 + s1c] = vp1;
        __syncthreads();
        if (ch + 1 < nch) {                    // issue next chunk's loads now
            const __bf16* Kn = Kwb + (size_t)((ch + 1) * 64) * HD;
            const __bf16* Vn = Vwb + (ch + 1) * 64;
            kp0 = *(const bfrag8*)(Kn + (size_t)s0r * HD + s0c);
            kp1 = *(const bfrag8*)(Kn + (size_t)s1r * HD + s1c);
            vp0 = *(const bfrag8*)(Vn + (size_t)s0r * SEQ + s0c);
            vp1 = *(const bfrag8*)(Vn + (size_t)s1r * SEQ + s1c);
        }

        ffrag4 acc[4] = { {0,0,0,0},{0,0,0,0},{0,0,0,0},{0,0,0,0} };
        #pragma unroll
        for (int g = 0; g < 4; ++g) {
            bfrag8 b0 = *(bfrag8*)&Ks[(g * 16 + l16) * 72 + quad * 8];
            bfrag8 b1 = *(bfrag8*)&Ks[(g * 16 + l16) * 72 + 32 + quad * 8];
            acc[g] = mfma16(qf0, b0, acc[g]);
            acc[g] = mfma16(qf1, b1, acc[g]);
        }
        #pragma unroll
        for (int r = 0; r < 4; ++r) {
            const int row = myrow + r;
            #pragma unroll
            for (int g = 0; g < 4; ++g) {
                int col = ch * 64 + g * 16 + l16;
                float p = (col <= row)
                        ? exp2f(acc[g][r] * SCALE2 - m_i[r]) * rl[r] : 0.f;
                Pw[(quad * 4 + r) * 68 + g * 16 + l16] = p;
            }
        }
        asm volatile("s_waitcnt lgkmcnt(0)" ::: "memory");  // wave-private tile ready

        // coalesced fp32 P stores: 4x dwordx4 per lane (256B per row segment)
        #pragma unroll
        for (int t = 0; t < 4; ++t) {
            int row = (lane >> 4) + t * 4;
            f32x4 v = *(f32x4*)&Pw[row * 68 + (lane & 15) * 4];
            __builtin_nontemporal_store(v,
                (f32x4*)(Pb + (size_t)(wrow + row) * SEQ + ch * 64 + (lane & 15) * 4));
        }

        // PV: rebuild A-frags (bf16) from the fp32 LDS tile
        #pragma unroll
        for (int h = 0; h < 2; ++h) {
            float4 p0 = *(float4*)&Pw[l16 * 68 + h * 32 + quad * 8];
            float4 p1 = *(float4*)&Pw[l16 * 68 + h * 32 + quad * 8 + 4];
            bfrag8 pa = { (__bf16)p0.x, (__bf16)p0.y, (__bf16)p0.z, (__bf16)p0.w,
                          (__bf16)p1.x, (__bf16)p1.y, (__bf16)p1.z, (__bf16)p1.w };
            #pragma unroll
            for (int t = 0; t < 4; ++t) {
                bfrag8 bv = *(bfrag8*)&Vts[(t * 16 + l16) * 72 + h * 32 + quad * 8];
                oacc[t] = mfma16(pa, bv, oacc[t]);
            }
        }
    }

    // ---- write O ----
    #pragma unroll
    for (int t = 0; t < 4; ++t)
        #pragma unroll
        for (int r = 0; r < 4; ++r)
            Ob[(size_t)(myrow + r) * HD + t * 16 + l16] = oacc[t][r];
}

extern "C" void kernel_launch(void* const* d_in, const int* in_sizes, int n_in,
                              void* d_out, int out_size, void* d_ws, size_t ws_size,
                              hipStream_t stream) {
    const float* Qg = (const float*)d_in[0];
    const float* Kg = (const float*)d_in[1];
    const float* Vg = (const float*)d_in[2];
    // d_in[3] (attn_mask) intentionally unused: mask is the fixed causal tril
    float* Og = (float*)d_out;
    float* Pg = Og + (size_t)NB * NH * SEQ * HD;

    // workspace: Kw (bf16, row-major) + Vtw (bf16, transposed [d][s]); 8.4 MB each
    __bf16* Kw  = (__bf16*)d_ws;
    __bf16* Vtw = Kw + (size_t)NB * NH * SEQ * HD;

    dim3 grid(SEQ / 64, NB * NH);
    cvt_kv<<<grid, dim3(256), 0, stream>>>(Kg, Vg, Kw, Vtw);
    attn_fwd<<<grid, dim3(256), 0, stream>>>(Qg, Kw, Vtw, Og, Pg);
}